// Round 1
// baseline (332.239 us; speedup 1.0000x reference)
//
#include <hip/hip_runtime.h>
#include <hip/hip_bf16.h>

#define S_LEN 1024
#define HD 64
#define NBH 64   // B*H = 4*16

typedef __attribute__((ext_vector_type(8))) short short8;   // 8 bf16 = 4 VGPRs
typedef __attribute__((ext_vector_type(4))) float floatx4;  // MFMA C/D

// fp32 -> bf16 round-to-nearest-even (inputs are finite normals)
__device__ __forceinline__ unsigned short f2bf(float f) {
  unsigned int u = __builtin_bit_cast(unsigned int, f);
  u += 0x7fffu + ((u >> 16) & 1u);
  return (unsigned short)(u >> 16);
}

// ---------------------------------------------------------------------------
// Kernel 1: MT[h][n][k] = bf16( 32*(n==k) + Wd[h]*W[h][k][n] )
// Layout [n][k] so main-GEMM B-operand fragments (contiguous along k) work.
// 65536 elements total.
// ---------------------------------------------------------------------------
__global__ __launch_bounds__(256) void prep_small_kernel(
    const float* __restrict__ W, const float* __restrict__ Wd,
    unsigned short* __restrict__ MT) {
  int idx = blockIdx.x * 256 + threadIdx.x;  // h*4096 + n*64 + k
  int h  = idx >> 12;
  int n  = (idx >> 6) & 63;
  int kk = idx & 63;
  float v = Wd[h] * W[(h << 12) + (kk << 6) + n];
  if (kk == n) v += 32.0f;
  MT[idx] = f2bf(v);
}

// ---------------------------------------------------------------------------
// Kernel 2: q'[bh] = q[bh] @ M_h  (S x 64 = S x 64 @ 64 x 64), output bf16.
// Grid (4 row-chunks, 64 bh), 256 threads = 4 waves, each wave 64 rows x 64 cols.
// ---------------------------------------------------------------------------
__global__ __launch_bounds__(256) void prep_q_kernel(
    const float* __restrict__ q, const unsigned short* __restrict__ MT,
    unsigned short* __restrict__ qp) {
  const int bh   = blockIdx.y;
  const int h    = bh & 15;
  const int wave = threadIdx.x >> 6;
  const int lane = threadIdx.x & 63;
  const int l15  = lane & 15;
  const int quad = lane >> 4;
  const int i0   = blockIdx.x * 256 + wave * 64;

  const float* __restrict__ qb = q + (size_t)bh * S_LEN * HD;
  const unsigned short* __restrict__ mt = MT + (h << 12);

  // B fragments: M_h^T rows are contiguous along k
  short8 bfrag[4][2];
#pragma unroll
  for (int nt = 0; nt < 4; nt++)
#pragma unroll
    for (int ks = 0; ks < 2; ks++)
      bfrag[nt][ks] = *(const short8*)(mt + (nt * 16 + l15) * HD + ks * 32 + quad * 8);

  // A fragments: 8 consecutive fp32 of a q row -> bf16
  short8 afrag[4][2];
#pragma unroll
  for (int mtile = 0; mtile < 4; mtile++)
#pragma unroll
    for (int ks = 0; ks < 2; ks++) {
      const float* src = qb + (size_t)(i0 + mtile * 16 + l15) * HD + ks * 32 + quad * 8;
      floatx4 a0 = *(const floatx4*)src;
      floatx4 a1 = *(const floatx4*)(src + 4);
      short8 f;
      f[0] = f2bf(a0[0]); f[1] = f2bf(a0[1]); f[2] = f2bf(a0[2]); f[3] = f2bf(a0[3]);
      f[4] = f2bf(a1[0]); f[5] = f2bf(a1[1]); f[6] = f2bf(a1[2]); f[7] = f2bf(a1[3]);
      afrag[mtile][ks] = f;
    }

  floatx4 acc[4][4];
#pragma unroll
  for (int mtile = 0; mtile < 4; mtile++)
#pragma unroll
    for (int nt = 0; nt < 4; nt++) {
      acc[mtile][nt] = (floatx4){0.f, 0.f, 0.f, 0.f};
#pragma unroll
      for (int ks = 0; ks < 2; ks++)
        acc[mtile][nt] = __builtin_amdgcn_mfma_f32_16x16x32_bf16(
            afrag[mtile][ks], bfrag[nt][ks], acc[mtile][nt], 0, 0, 0);
    }

  unsigned short* __restrict__ qpb = qp + (size_t)bh * S_LEN * HD;
#pragma unroll
  for (int mtile = 0; mtile < 4; mtile++)
#pragma unroll
    for (int nt = 0; nt < 4; nt++)
#pragma unroll
      for (int r = 0; r < 4; r++) {
        int row = i0 + mtile * 16 + quad * 4 + r;
        int col = nt * 16 + l15;
        qpb[row * HD + col] = f2bf(acc[mtile][nt][r]);
      }
}

// ---------------------------------------------------------------------------
// Kernel 3: d[bh] = q'_bf16 @ k^T + Wd_h*b_h.  NT GEMM, K=64.
// Grid (8 col-tiles, 8 row-tiles, 64 bh); 256 threads = 4 waves (2x2),
// each wave computes 64x64 via 4x4 tiles of 16x16x32 MFMA. No LDS.
// ---------------------------------------------------------------------------
__global__ __launch_bounds__(256) void main_kernel(
    const unsigned short* __restrict__ qp, const float* __restrict__ kmat,
    const float* __restrict__ b, const float* __restrict__ Wd,
    float* __restrict__ out) {
  const int bh   = blockIdx.z;
  const int h    = bh & 15;
  const int wave = threadIdx.x >> 6;
  const int lane = threadIdx.x & 63;
  const int l15  = lane & 15;
  const int quad = lane >> 4;
  const int row0 = blockIdx.y * 128 + (wave >> 1) * 64;
  const int col0 = blockIdx.x * 128 + (wave & 1) * 64;

  const unsigned short* __restrict__ qb = qp + (size_t)bh * S_LEN * HD;
  const float* __restrict__ kb = kmat + (size_t)bh * S_LEN * HD;

  // A fragments: q' rows, contiguous bf16
  short8 afrag[4][2];
#pragma unroll
  for (int mtile = 0; mtile < 4; mtile++)
#pragma unroll
    for (int ks = 0; ks < 2; ks++)
      afrag[mtile][ks] =
          *(const short8*)(qb + (row0 + mtile * 16 + l15) * HD + ks * 32 + quad * 8);

  // B fragments: k rows (j index), fp32 -> bf16 on the fly
  short8 bfrag[4][2];
#pragma unroll
  for (int nt = 0; nt < 4; nt++)
#pragma unroll
    for (int ks = 0; ks < 2; ks++) {
      const float* src = kb + (size_t)(col0 + nt * 16 + l15) * HD + ks * 32 + quad * 8;
      floatx4 a0 = *(const floatx4*)src;
      floatx4 a1 = *(const floatx4*)(src + 4);
      short8 f;
      f[0] = f2bf(a0[0]); f[1] = f2bf(a0[1]); f[2] = f2bf(a0[2]); f[3] = f2bf(a0[3]);
      f[4] = f2bf(a1[0]); f[5] = f2bf(a1[1]); f[6] = f2bf(a1[2]); f[7] = f2bf(a1[3]);
      bfrag[nt][ks] = f;
    }

  floatx4 acc[4][4];
#pragma unroll
  for (int mtile = 0; mtile < 4; mtile++)
#pragma unroll
    for (int nt = 0; nt < 4; nt++) {
      acc[mtile][nt] = (floatx4){0.f, 0.f, 0.f, 0.f};
#pragma unroll
      for (int ks = 0; ks < 2; ks++)
        acc[mtile][nt] = __builtin_amdgcn_mfma_f32_16x16x32_bf16(
            afrag[mtile][ks], bfrag[nt][ks], acc[mtile][nt], 0, 0, 0);
    }

  const float cbias = Wd[h] * b[h];
  float* __restrict__ ob = out + (size_t)bh * S_LEN * S_LEN;
#pragma unroll
  for (int mtile = 0; mtile < 4; mtile++)
#pragma unroll
    for (int r = 0; r < 4; r++) {
      int row = row0 + mtile * 16 + quad * 4 + r;
      float* orow = ob + (size_t)row * S_LEN + col0;
#pragma unroll
      for (int nt = 0; nt < 4; nt++)
        __builtin_nontemporal_store(acc[mtile][nt][r] + cbias, orow + nt * 16 + l15);
    }
}

extern "C" void kernel_launch(void* const* d_in, const int* in_sizes, int n_in,
                              void* d_out, int out_size, void* d_ws, size_t ws_size,
                              hipStream_t stream) {
  const float* q  = (const float*)d_in[0];
  const float* k  = (const float*)d_in[1];
  const float* W  = (const float*)d_in[2];
  const float* b  = (const float*)d_in[3];
  const float* Wd = (const float*)d_in[4];
  float* out = (float*)d_out;

  // workspace: q' bf16 (64*1024*64 = 4M ushorts = 8 MB), then MT (128 KB)
  unsigned short* qp = (unsigned short*)d_ws;
  unsigned short* MT = qp + (size_t)NBH * S_LEN * HD;

  prep_small_kernel<<<256, 256, 0, stream>>>(W, Wd, MT);
  prep_q_kernel<<<dim3(4, NBH), 256, 0, stream>>>(q, MT, qp);
  main_kernel<<<dim3(8, 8, NBH), 256, 0, stream>>>(qp, k, b, Wd, out);
}

// Round 2
// 306.773 us; speedup vs baseline: 1.0830x; 1.0830x over previous
//
#include <hip/hip_runtime.h>

#define S_LEN 1024
#define HD 64
#define NBH 64   // B*H = 4*16

typedef __attribute__((ext_vector_type(8))) short short8;            // 8 bf16
typedef __attribute__((ext_vector_type(4))) float floatx4;
typedef __attribute__((ext_vector_type(4))) unsigned short ushort4v; // 4 bf16

// fp32 -> bf16 round-to-nearest-even
__device__ __forceinline__ unsigned short f2bf(float f) {
  unsigned int u = __builtin_bit_cast(unsigned int, f);
  u += 0x7fffu + ((u >> 16) & 1u);
  return (unsigned short)(u >> 16);
}

// ---------------------------------------------------------------------------
// Kernel 1: MT[h][n][k] = bf16( 32*(n==k) + Wd[h]*W[h][k][n] )   (65536 elems)
// ---------------------------------------------------------------------------
__global__ __launch_bounds__(256) void prep_small_kernel(
    const float* __restrict__ W, const float* __restrict__ Wd,
    unsigned short* __restrict__ MT) {
  int idx = blockIdx.x * 256 + threadIdx.x;  // h*4096 + n*64 + k
  int h  = idx >> 12;
  int n  = (idx >> 6) & 63;
  int kk = idx & 63;
  float v = Wd[h] * W[(h << 12) + (kk << 6) + n];
  if (kk == n) v += 32.0f;
  MT[idx] = f2bf(v);
}

// ---------------------------------------------------------------------------
// Kernel 2: k' = bf16(k), elementwise. 4M elems, 4 per thread.
// ---------------------------------------------------------------------------
__global__ __launch_bounds__(256) void convert_k_kernel(
    const float* __restrict__ k, unsigned short* __restrict__ kp) {
  size_t t = (size_t)blockIdx.x * 256 + threadIdx.x;  // 0..1M-1
  floatx4 v = *(const floatx4*)(k + t * 4);
  ushort4v o;
  o[0] = f2bf(v[0]); o[1] = f2bf(v[1]); o[2] = f2bf(v[2]); o[3] = f2bf(v[3]);
  *(ushort4v*)(kp + t * 4) = o;
}

// ---------------------------------------------------------------------------
// Kernel 3: q'[bh] = bf16( q[bh] @ M_h ).  Grid (16, 64); wave does 16 rows.
// ---------------------------------------------------------------------------
__global__ __launch_bounds__(256) void prep_q_kernel(
    const float* __restrict__ q, const unsigned short* __restrict__ MT,
    unsigned short* __restrict__ qp) {
  const int bh   = blockIdx.y;
  const int h    = bh & 15;
  const int wave = threadIdx.x >> 6;
  const int lane = threadIdx.x & 63;
  const int l15  = lane & 15;
  const int quad = lane >> 4;
  const int i0   = blockIdx.x * 64 + wave * 16;

  const float* __restrict__ qb = q + (size_t)bh * S_LEN * HD;
  const unsigned short* __restrict__ mt = MT + (h << 12);

  short8 bfrag[4][2];
#pragma unroll
  for (int nt = 0; nt < 4; nt++)
#pragma unroll
    for (int ks = 0; ks < 2; ks++)
      bfrag[nt][ks] = *(const short8*)(mt + (nt * 16 + l15) * HD + ks * 32 + quad * 8);

  short8 afrag[2];
#pragma unroll
  for (int ks = 0; ks < 2; ks++) {
    const float* src = qb + (size_t)(i0 + l15) * HD + ks * 32 + quad * 8;
    floatx4 a0 = *(const floatx4*)src;
    floatx4 a1 = *(const floatx4*)(src + 4);
    short8 f;
    f[0] = f2bf(a0[0]); f[1] = f2bf(a0[1]); f[2] = f2bf(a0[2]); f[3] = f2bf(a0[3]);
    f[4] = f2bf(a1[0]); f[5] = f2bf(a1[1]); f[6] = f2bf(a1[2]); f[7] = f2bf(a1[3]);
    afrag[ks] = f;
  }

  floatx4 acc[4];
#pragma unroll
  for (int nt = 0; nt < 4; nt++) {
    acc[nt] = (floatx4){0.f, 0.f, 0.f, 0.f};
#pragma unroll
    for (int ks = 0; ks < 2; ks++)
      acc[nt] = __builtin_amdgcn_mfma_f32_16x16x32_bf16(afrag[ks], bfrag[nt][ks],
                                                        acc[nt], 0, 0, 0);
  }

  unsigned short* __restrict__ qpb = qp + (size_t)bh * S_LEN * HD;
#pragma unroll
  for (int nt = 0; nt < 4; nt++)
#pragma unroll
    for (int r = 0; r < 4; r++)
      qpb[(i0 + quad * 4 + r) * HD + nt * 16 + l15] = f2bf(acc[nt][r]);
}

// ---------------------------------------------------------------------------
// Kernel 4: d[bh] = q' @ k'^T + Wd_h*b_h.  Both operands bf16, 16B frag loads.
// Grid (8, 8, 64); 4 waves (2x2), each 64x64. Epilogue: LDS transpose so
// stores are global_store_dwordx4 (wave covers 4 x 256 B contiguous).
// ---------------------------------------------------------------------------
#define LPAD 68  // 68%32=4 -> write-phase 2-way bank alias (free); 16B-aligned rows
__global__ __launch_bounds__(256) void main_kernel(
    const unsigned short* __restrict__ qp, const unsigned short* __restrict__ kp,
    const float* __restrict__ b, const float* __restrict__ Wd,
    float* __restrict__ out) {
  __shared__ __align__(16) float lds[4 * 32 * LPAD];  // 34816 B

  const int bh   = blockIdx.z;
  const int h    = bh & 15;
  const int wave = threadIdx.x >> 6;
  const int lane = threadIdx.x & 63;
  const int l15  = lane & 15;
  const int quad = lane >> 4;
  const int row0 = blockIdx.y * 128 + (wave >> 1) * 64;
  const int col0 = blockIdx.x * 128 + (wave & 1) * 64;

  const unsigned short* __restrict__ qb = qp + ((size_t)bh << 16);
  const unsigned short* __restrict__ kb = kp + ((size_t)bh << 16);

  short8 afrag[4][2], bfrag[4][2];
#pragma unroll
  for (int t = 0; t < 4; t++)
#pragma unroll
    for (int ks = 0; ks < 2; ks++) {
      afrag[t][ks] = *(const short8*)(qb + (row0 + t * 16 + l15) * HD + ks * 32 + quad * 8);
      bfrag[t][ks] = *(const short8*)(kb + (col0 + t * 16 + l15) * HD + ks * 32 + quad * 8);
    }

  const float cbias = Wd[h] * b[h];
  floatx4 acc[4][4];
#pragma unroll
  for (int mtile = 0; mtile < 4; mtile++)
#pragma unroll
    for (int nt = 0; nt < 4; nt++) {
      acc[mtile][nt] = (floatx4){cbias, cbias, cbias, cbias};  // bias folded into C
#pragma unroll
      for (int ks = 0; ks < 2; ks++)
        acc[mtile][nt] = __builtin_amdgcn_mfma_f32_16x16x32_bf16(
            afrag[mtile][ks], bfrag[nt][ks], acc[mtile][nt], 0, 0, 0);
    }

  // Epilogue: per-wave private LDS region, 2 chunks of 32 rows. No barriers —
  // within-wave LDS ordering via explicit lgkmcnt(0).
  float* __restrict__ wlds = lds + wave * (32 * LPAD);
  float* __restrict__ ob = out + ((size_t)bh << 20);
#pragma unroll
  for (int c = 0; c < 2; ++c) {
#pragma unroll
    for (int mr = 0; mr < 2; ++mr) {
      int mtile = 2 * c + mr;
#pragma unroll
      for (int nt = 0; nt < 4; nt++)
#pragma unroll
        for (int r = 0; r < 4; r++)
          wlds[(mr * 16 + quad * 4 + r) * LPAD + nt * 16 + l15] = acc[mtile][nt][r];
    }
    __asm__ volatile("s_waitcnt lgkmcnt(0)" ::: "memory");
#pragma unroll
    for (int g = 0; g < 8; ++g) {
      int row = g * 4 + quad;
      floatx4 v = *(const floatx4*)(wlds + row * LPAD + l15 * 4);
      __builtin_nontemporal_store(
          v, (floatx4*)(ob + (size_t)(row0 + c * 32 + row) * S_LEN + col0 + l15 * 4));
    }
    __asm__ volatile("s_waitcnt lgkmcnt(0)" ::: "memory");
  }
}

extern "C" void kernel_launch(void* const* d_in, const int* in_sizes, int n_in,
                              void* d_out, int out_size, void* d_ws, size_t ws_size,
                              hipStream_t stream) {
  const float* q  = (const float*)d_in[0];
  const float* k  = (const float*)d_in[1];
  const float* W  = (const float*)d_in[2];
  const float* b  = (const float*)d_in[3];
  const float* Wd = (const float*)d_in[4];
  float* out = (float*)d_out;

  unsigned short* qp = (unsigned short*)d_ws;                 // 8 MB
  unsigned short* kp = qp + (size_t)NBH * S_LEN * HD;         // 8 MB
  unsigned short* MT = kp + (size_t)NBH * S_LEN * HD;         // 128 KB

  prep_small_kernel<<<256, 256, 0, stream>>>(W, Wd, MT);
  convert_k_kernel<<<4096, 256, 0, stream>>>(k, kp);
  prep_q_kernel<<<dim3(16, NBH), 256, 0, stream>>>(q, MT, qp);
  main_kernel<<<dim3(8, 8, NBH), 256, 0, stream>>>(qp, kp, b, Wd, out);
}